// Round 1
// baseline (4447.204 us; speedup 1.0000x reference)
//
#include <hip/hip_runtime.h>
#include <hip/hip_fp16.h>

typedef _Float16 f16;
typedef __attribute__((ext_vector_type(8))) _Float16 f16x8;
typedef __attribute__((ext_vector_type(16))) float f32x16;

#define NB 2048      // batch
#define SEQ 64       // warmup sequence length
#define NF 3         // features
#define NU 512       // units
#define N4U 2048     // 4*units
#define NSTEP 127    // 64 warmup + 63 rollout
#define NBLK 256     // 16 b-tiles x 16 u-groups
#define WT_LD 520    // 512 + 8 fp16 pad (keeps 16B align, breaks pow2 bank stride)

#define SM_WT_BYTES (128 * WT_LD * 2)          // 133120 B: W^T slice, fp16
#define SM_XS_OFF   SM_WT_BYTES                // x stage: float[128*3]
#define SM_TOTAL    (SM_XS_OFF + 128 * 3 * 4)  // 134656 B

__device__ __forceinline__ float fast_rcp(float x) { return __builtin_amdgcn_rcpf(x); }
__device__ __forceinline__ float sigf(float x) { return fast_rcp(1.f + __expf(-x)); }
__device__ __forceinline__ float tanhf_fast(float x) {
    float a = fabsf(x);
    float e = __expf(-2.f * a);
    float t = (1.f - e) * fast_rcp(1.f + e);
    return copysignf(t, x);
}

__global__ __launch_bounds__(256, 1)
void lstm_feedback_kernel(const float* __restrict__ inputs, const float* __restrict__ kernw,
                          const float* __restrict__ rec, const float* __restrict__ bias,
                          const float* __restrict__ dw, const float* __restrict__ db,
                          float* __restrict__ out, f16* __restrict__ hbuf,
                          unsigned* __restrict__ bar)
{
    extern __shared__ char smem[];
    f16* Wt = (f16*)smem;                         // [128 cols][WT_LD k] fp16
    float* x_s = (float*)(smem + SM_XS_OFF);      // [128][3]

    const int tid = threadIdx.x;
    const int bid = blockIdx.x;
    const int ug = bid & 15;          // u-group (0..15)
    const int bt = bid >> 4;          // b-tile  (0..15)
    const int uBase = ug * 32;
    const int bBase = bt * 128;
    const int w  = tid >> 6;          // wave 0..3 (splits b)
    const int l  = tid & 63;
    const int l31 = l & 31;
    const int hf  = l >> 5;           // half-wave

    // ---- zero the output (poisoned 0xAA each launch; we atomicAdd into it later)
    {
        float* o = out + bid * 1536;
        #pragma unroll
        for (int i = 0; i < 6; ++i) o[i * 256 + tid] = 0.f;
    }

    // ---- stage W^T slice into LDS as fp16 (cols = 4 gates x 32 u), once
    {
        const int c  = tid & 127;
        const int kk = tid >> 7;
        const int gcol = ((c >> 5) * 512) + uBase + (c & 31);
        for (int k = kk; k < NU; k += 2)
            Wt[c * WT_LD + k] = (f16)rec[k * N4U + gcol];
    }

    // ---- per-lane constants: input-kernel cols, bias, dense_w rows, dense_b
    float kr[4][3], br[4], dwr[3], dbr[3];
    #pragma unroll
    for (int ct = 0; ct < 4; ++ct) {
        const int gcol = ct * 512 + uBase + l31;
        #pragma unroll
        for (int f = 0; f < 3; ++f) kr[ct][f] = kernw[f * N4U + gcol];
        br[ct] = bias[gcol];
    }
    {
        const int u = uBase + l31;
        #pragma unroll
        for (int j = 0; j < 3; ++j) { dwr[j] = dw[u * 3 + j]; dbr[j] = db[j]; }
    }
    __syncthreads();

    float c_reg[16];
    #pragma unroll
    for (int r = 0; r < 16; ++r) c_reg[r] = 0.f;

    const size_t HB = (size_t)NB * NU;
    const int bW = bBase + w * 32;                                 // wave's first b row
    const size_t aoff = (size_t)(bW + l31) * NU + hf * 8;          // A-frag lane offset
    const f16* bptr = Wt + (size_t)l31 * WT_LD + hf * 8;           // B-frag lane base

    for (int s = 0; s < NSTEP; ++s) {
        // ---- stage x for this step (warmup: inputs[:,s,:]; rollout: prev pred from out)
        if (tid < 128) {
            const int b = bBase + tid;
            const float* xp = (s < SEQ)
                ? inputs + ((size_t)b * SEQ + s) * NF
                : out + ((size_t)(s - SEQ) * NB + b) * NF;
            x_s[tid * 3 + 0] = xp[0];
            x_s[tid * 3 + 1] = xp[1];
            x_s[tid * 3 + 2] = xp[2];
        }
        __syncthreads();

        f32x16 acc0 = {}, acc1 = {}, acc2 = {}, acc3 = {};
        if (s > 0) {
            const f16* ap = hbuf + (size_t)(s & 1) * HB + aoff;
            #pragma unroll 8
            for (int kt = 0; kt < 32; ++kt) {
                const int k0 = kt * 16;
                f16x8 a  = *(const f16x8*)(ap + k0);
                f16x8 b0 = *(const f16x8*)(bptr + 0 * 32 * WT_LD + k0);
                f16x8 b1 = *(const f16x8*)(bptr + 1 * 32 * WT_LD + k0);
                f16x8 b2 = *(const f16x8*)(bptr + 2 * 32 * WT_LD + k0);
                f16x8 b3 = *(const f16x8*)(bptr + 3 * 32 * WT_LD + k0);
                acc0 = __builtin_amdgcn_mfma_f32_32x32x16_f16(a, b0, acc0, 0, 0, 0);
                acc1 = __builtin_amdgcn_mfma_f32_32x32x16_f16(a, b1, acc1, 0, 0, 0);
                acc2 = __builtin_amdgcn_mfma_f32_32x32x16_f16(a, b2, acc2, 0, 0, 0);
                acc3 = __builtin_amdgcn_mfma_f32_32x32x16_f16(a, b3, acc3, 0, 0, 0);
            }
        }

        // ---- gates + state update + h write (+ pred contribution on rollout)
        f16* hw = hbuf + (size_t)((s & 1) ^ 1) * HB;
        const int n_out = s - (SEQ - 1);   // out slot receiving pred this step
        #pragma unroll
        for (int r = 0; r < 16; ++r) {
            const int mloc = (w << 5) + ((r & 3) + ((r >> 2) << 3) + (hf << 2));
            const float x0 = x_s[mloc * 3 + 0];
            const float x1 = x_s[mloc * 3 + 1];
            const float x2 = x_s[mloc * 3 + 2];
            float z0 = acc0[r] + x0 * kr[0][0] + x1 * kr[0][1] + x2 * kr[0][2] + br[0];
            float z1 = acc1[r] + x0 * kr[1][0] + x1 * kr[1][1] + x2 * kr[1][2] + br[1];
            float z2 = acc2[r] + x0 * kr[2][0] + x1 * kr[2][1] + x2 * kr[2][2] + br[2];
            float z3 = acc3[r] + x0 * kr[3][0] + x1 * kr[3][1] + x2 * kr[3][2] + br[3];
            const float gi = sigf(z0);
            const float gf = sigf(z1);
            const float gg = tanhf_fast(z2);
            const float go = sigf(z3);
            const float cv = gf * c_reg[r] + gi * gg;
            c_reg[r] = cv;
            const float h2 = go * tanhf_fast(cv);
            hw[(size_t)(bBase + mloc) * NU + uBase + l31] = (f16)h2;

            if (n_out >= 0) {
                #pragma unroll
                for (int j = 0; j < 3; ++j) {
                    float v = h2 * dwr[j];
                    if (ug == 0 && l31 == 0) v += dbr[j];   // dense bias exactly once
                    #pragma unroll
                    for (int m = 1; m < 32; m <<= 1) v += __shfl_xor(v, m, 64);
                    if (l31 == r)   // spread the atomic duty across lanes
                        atomicAdd(&out[((size_t)n_out * NB + bBase + mloc) * 3 + j], v);
                }
            }
        }

        // ---- grid barrier (monotonic counter; release h writes, acquire for next read)
        if (s < NSTEP - 1) {
            __syncthreads();
            if (tid == 0) {
                __threadfence();
                __hip_atomic_fetch_add(bar, 1u, __ATOMIC_RELEASE, __HIP_MEMORY_SCOPE_AGENT);
                const unsigned target = (unsigned)(s + 1) * NBLK;
                while (__hip_atomic_load(bar, __ATOMIC_RELAXED, __HIP_MEMORY_SCOPE_AGENT) < target) {}
                __threadfence();
            }
            __syncthreads();
        }
    }
}

extern "C" void kernel_launch(void* const* d_in, const int* in_sizes, int n_in,
                              void* d_out, int out_size, void* d_ws, size_t ws_size,
                              hipStream_t stream) {
    const float* inputs = (const float*)d_in[0];
    const float* kernw  = (const float*)d_in[1];
    const float* rec    = (const float*)d_in[2];
    const float* bias   = (const float*)d_in[3];
    const float* dw     = (const float*)d_in[4];
    const float* db     = (const float*)d_in[5];
    float* out = (float*)d_out;

    unsigned* bar = (unsigned*)d_ws;                  // barrier counter at ws[0]
    f16* hbuf = (f16*)((char*)d_ws + 1024);           // double-buffered h: 2 x 2 MB

    // zero barrier counter (ws is poisoned 0xAA before every launch)
    hipMemsetAsync(d_ws, 0, 1024, stream);

    hipFuncSetAttribute(reinterpret_cast<const void*>(lstm_feedback_kernel),
                        hipFuncAttributeMaxDynamicSharedMemorySize, SM_TOTAL);

    void* args[] = { (void*)&inputs, (void*)&kernw, (void*)&rec, (void*)&bias,
                     (void*)&dw, (void*)&db, (void*)&out, (void*)&hbuf, (void*)&bar };
    hipLaunchCooperativeKernel(reinterpret_cast<const void*>(lstm_feedback_kernel),
                               dim3(NBLK), dim3(256), args, SM_TOTAL, stream);
}

// Round 2
// 2907.838 us; speedup vs baseline: 1.5294x; 1.5294x over previous
//
#include <hip/hip_runtime.h>
#include <hip/hip_fp16.h>

typedef _Float16 f16;
typedef __attribute__((ext_vector_type(8))) _Float16 f16x8;
typedef __attribute__((ext_vector_type(16))) float f32x16;

#define NB 2048      // batch
#define SEQ 64       // warmup sequence length
#define NF 3         // features
#define NU 512       // units
#define N4U 2048     // 4*units
#define NSTEP 127    // 64 warmup + 63 rollout
#define WT_LD 520    // 512 + 8 fp16 pad

#define SM_WT_BYTES (128 * WT_LD * 2)          // 133120 B: W^T slice, fp16
#define SM_XS_OFF   SM_WT_BYTES                // x stage: float[128*3]
#define SM_TOTAL    (SM_XS_OFF + 128 * 3 * 4)  // 134656 B

// ws layout
#define WS_PP_OFF   (16 * 1024)                // after 16 barrier counters (1KB stride each)
#define WS_H_OFF    (1u << 20)                 // h double buffer: 2 x 2 MB fp16
#define PP_PAR_STRIDE (16 * 16 * 128 * 3)      // floats per parity buffer
#define PP_BT_STRIDE  (16 * 128 * 3)
#define PP_UG_STRIDE  (128 * 3)

__device__ __forceinline__ float fast_rcp(float x) { return __builtin_amdgcn_rcpf(x); }
__device__ __forceinline__ float sigf(float x) { return fast_rcp(1.f + __expf(-x)); }
__device__ __forceinline__ float tanhf_fast(float x) {
    float a = fabsf(x);
    float e = __expf(-2.f * a);
    float t = (1.f - e) * fast_rcp(1.f + e);
    return copysignf(t, x);
}

__global__ __launch_bounds__(256, 1)
void lstm_feedback_kernel(const float* __restrict__ inputs, const float* __restrict__ kernw,
                          const float* __restrict__ rec, const float* __restrict__ bias,
                          const float* __restrict__ dw, const float* __restrict__ db,
                          float* __restrict__ out, float* __restrict__ pp,
                          f16* __restrict__ hbuf, unsigned* __restrict__ bar)
{
    extern __shared__ char smem[];
    f16* Wt = (f16*)smem;                         // [128 cols][WT_LD k] fp16
    float* x_s = (float*)(smem + SM_XS_OFF);      // [128][3]

    const int tid = threadIdx.x;
    const int bid = blockIdx.x;
    // Swizzle so the 16 blocks of one bt share bid%8 (same XCD under round-robin).
    const int xcd = bid & 7;
    const int jj  = bid >> 3;
    const int bt  = (xcd << 1) | (jj & 1);   // b-tile 0..15 (the sync domain)
    const int ug  = jj >> 1;                 // u-group 0..15
    const int uBase = ug * 32;
    const int bBase = bt * 128;
    const int w  = tid >> 6;          // wave 0..3 (splits b)
    const int l  = tid & 63;
    const int l31 = l & 31;
    const int hf  = l >> 5;           // half-wave
    unsigned* mybar = bar + bt * 256; // 1KB-strided counters, one per bt

    // ---- stage W^T slice into LDS as fp16 (cols = 4 gates x 32 u), once
    {
        const int c  = tid & 127;
        const int kk = tid >> 7;
        const int gcol = ((c >> 5) * 512) + uBase + (c & 31);
        for (int k = kk; k < NU; k += 2)
            Wt[c * WT_LD + k] = (f16)rec[k * N4U + gcol];
    }

    // ---- per-lane constants
    float kr[4][3], br[4], dwr[3], dbr[3];
    #pragma unroll
    for (int ct = 0; ct < 4; ++ct) {
        const int gcol = ct * 512 + uBase + l31;
        #pragma unroll
        for (int f = 0; f < 3; ++f) kr[ct][f] = kernw[f * N4U + gcol];
        br[ct] = bias[gcol];
    }
    {
        const int u = uBase + l31;
        #pragma unroll
        for (int j = 0; j < 3; ++j) { dwr[j] = dw[u * 3 + j]; dbr[j] = db[j]; }
    }
    __syncthreads();

    float c_reg[16];
    #pragma unroll
    for (int r = 0; r < 16; ++r) c_reg[r] = 0.f;

    const size_t HB = (size_t)NB * NU;
    const int bW = bBase + w * 32;
    const size_t aoff = (size_t)(bW + l31) * NU + hf * 8;
    const f16* bptr = Wt + (size_t)l31 * WT_LD + hf * 8;

    for (int s = 0; s < NSTEP; ++s) {
        // ---- wait: the 16 blocks of this bt have all released step s-1
        if (s > 0) {
            if (tid == 0) {
                const unsigned tgt = (unsigned)s * 16u;
                while (__hip_atomic_load(mybar, __ATOMIC_RELAXED, __HIP_MEMORY_SCOPE_AGENT) < tgt) {}
                __threadfence();
            }
            __syncthreads();
        }

        // ---- stage x (warmup: inputs[:,s,:]; rollout: sum of pred partials)
        if (tid < 128) {
            float v0, v1, v2;
            if (s < SEQ) {
                const float* xp = inputs + ((size_t)(bBase + tid) * SEQ + s) * NF;
                v0 = xp[0]; v1 = xp[1]; v2 = xp[2];
            } else {
                const float* p = pp + (size_t)((s + 1) & 1) * PP_PAR_STRIDE
                               + bt * PP_BT_STRIDE + tid * 3;
                v0 = dbr[0]; v1 = dbr[1]; v2 = dbr[2];
                #pragma unroll
                for (int g = 0; g < 16; ++g) {
                    v0 += p[g * PP_UG_STRIDE + 0];
                    v1 += p[g * PP_UG_STRIDE + 1];
                    v2 += p[g * PP_UG_STRIDE + 2];
                }
                if (ug == 0) {  // final output: each pred element stored exactly once
                    float* o = out + ((size_t)(s - SEQ) * NB + bBase + tid) * 3;
                    o[0] = v0; o[1] = v1; o[2] = v2;
                }
            }
            x_s[tid * 3 + 0] = v0;
            x_s[tid * 3 + 1] = v1;
            x_s[tid * 3 + 2] = v2;
        }
        __syncthreads();

        f32x16 acc0 = {}, acc1 = {}, acc2 = {}, acc3 = {};
        if (s > 0) {
            const f16* ap = hbuf + (size_t)(s & 1) * HB + aoff;
            #pragma unroll 8
            for (int kt = 0; kt < 32; ++kt) {
                const int k0 = kt * 16;
                f16x8 a  = *(const f16x8*)(ap + k0);
                f16x8 b0 = *(const f16x8*)(bptr + 0 * 32 * WT_LD + k0);
                f16x8 b1 = *(const f16x8*)(bptr + 1 * 32 * WT_LD + k0);
                f16x8 b2 = *(const f16x8*)(bptr + 2 * 32 * WT_LD + k0);
                f16x8 b3 = *(const f16x8*)(bptr + 3 * 32 * WT_LD + k0);
                acc0 = __builtin_amdgcn_mfma_f32_32x32x16_f16(a, b0, acc0, 0, 0, 0);
                acc1 = __builtin_amdgcn_mfma_f32_32x32x16_f16(a, b1, acc1, 0, 0, 0);
                acc2 = __builtin_amdgcn_mfma_f32_32x32x16_f16(a, b2, acc2, 0, 0, 0);
                acc3 = __builtin_amdgcn_mfma_f32_32x32x16_f16(a, b3, acc3, 0, 0, 0);
            }
        }

        // ---- gates + state update + h write (+ pred partial on rollout)
        f16* hw = hbuf + (size_t)((s & 1) ^ 1) * HB;
        const int n_out = s - (SEQ - 1);
        float* ppw = pp + (size_t)(s & 1) * PP_PAR_STRIDE + bt * PP_BT_STRIDE + ug * PP_UG_STRIDE;
        #pragma unroll
        for (int r = 0; r < 16; ++r) {
            const int mrow = (r & 3) + ((r >> 2) << 3) + (hf << 2);
            const int mloc = (w << 5) + mrow;
            const float x0 = x_s[mloc * 3 + 0];
            const float x1 = x_s[mloc * 3 + 1];
            const float x2 = x_s[mloc * 3 + 2];
            float z0 = acc0[r] + x0 * kr[0][0] + x1 * kr[0][1] + x2 * kr[0][2] + br[0];
            float z1 = acc1[r] + x0 * kr[1][0] + x1 * kr[1][1] + x2 * kr[1][2] + br[1];
            float z2 = acc2[r] + x0 * kr[2][0] + x1 * kr[2][1] + x2 * kr[2][2] + br[2];
            float z3 = acc3[r] + x0 * kr[3][0] + x1 * kr[3][1] + x2 * kr[3][2] + br[3];
            const float gi = sigf(z0);
            const float gf = sigf(z1);
            const float gg = tanhf_fast(z2);
            const float go = sigf(z3);
            const float cv = gf * c_reg[r] + gi * gg;
            c_reg[r] = cv;
            const float h2 = go * tanhf_fast(cv);
            hw[(size_t)(bBase + mloc) * NU + uBase + l31] = (f16)h2;

            if (n_out >= 0) {
                #pragma unroll
                for (int j = 0; j < 3; ++j) {
                    float v = h2 * dwr[j];
                    #pragma unroll
                    for (int m = 1; m < 32; m <<= 1) v += __shfl_xor(v, m, 64);
                    if (l31 == r) ppw[mloc * 3 + j] = v;   // per-half-wave row partial
                }
            }
        }

        // ---- release: stores drained (barrier emits vmcnt(0)), fence, bump counter
        __syncthreads();
        if (tid == 0) {
            __threadfence();
            __hip_atomic_fetch_add(mybar, 1u, __ATOMIC_RELAXED, __HIP_MEMORY_SCOPE_AGENT);
        }
    }

    // ---- epilogue: pred slot 63 (partials from step 126, parity 0)
    if (ug == 0) {
        if (tid == 0) {
            while (__hip_atomic_load(mybar, __ATOMIC_RELAXED, __HIP_MEMORY_SCOPE_AGENT)
                   < (unsigned)NSTEP * 16u) {}
            __threadfence();
        }
        __syncthreads();
        if (tid < 128) {
            const float* p = pp + bt * PP_BT_STRIDE + tid * 3;   // parity 0
            float v0 = dbr[0], v1 = dbr[1], v2 = dbr[2];
            #pragma unroll
            for (int g = 0; g < 16; ++g) {
                v0 += p[g * PP_UG_STRIDE + 0];
                v1 += p[g * PP_UG_STRIDE + 1];
                v2 += p[g * PP_UG_STRIDE + 2];
            }
            float* o = out + ((size_t)63 * NB + bBase + tid) * 3;
            o[0] = v0; o[1] = v1; o[2] = v2;
        }
    }
}

extern "C" void kernel_launch(void* const* d_in, const int* in_sizes, int n_in,
                              void* d_out, int out_size, void* d_ws, size_t ws_size,
                              hipStream_t stream) {
    const float* inputs = (const float*)d_in[0];
    const float* kernw  = (const float*)d_in[1];
    const float* rec    = (const float*)d_in[2];
    const float* bias   = (const float*)d_in[3];
    const float* dw     = (const float*)d_in[4];
    const float* db     = (const float*)d_in[5];
    float* out = (float*)d_out;

    unsigned* bar = (unsigned*)d_ws;                       // 16 counters, 1KB stride
    float* pp  = (float*)((char*)d_ws + WS_PP_OFF);        // pred partials, 2 parities
    f16* hbuf  = (f16*)((char*)d_ws + WS_H_OFF);           // double-buffered h: 2 x 2 MB

    hipMemsetAsync(d_ws, 0, 16 * 1024, stream);            // zero barrier counters

    hipFuncSetAttribute(reinterpret_cast<const void*>(lstm_feedback_kernel),
                        hipFuncAttributeMaxDynamicSharedMemorySize, SM_TOTAL);

    void* args[] = { (void*)&inputs, (void*)&kernw, (void*)&rec, (void*)&bias,
                     (void*)&dw, (void*)&db, (void*)&out, (void*)&pp,
                     (void*)&hbuf, (void*)&bar };
    hipLaunchCooperativeKernel(reinterpret_cast<const void*>(lstm_feedback_kernel),
                               dim3(256), dim3(256), args, SM_TOTAL, stream);
}

// Round 3
// 2559.991 us; speedup vs baseline: 1.7372x; 1.1359x over previous
//
#include <hip/hip_runtime.h>
#include <hip/hip_fp16.h>

typedef _Float16 f16;
typedef __attribute__((ext_vector_type(8))) _Float16 f16x8;
typedef __attribute__((ext_vector_type(16))) float f32x16;

#define NB 2048      // batch
#define SEQ 64       // warmup sequence length
#define NF 3         // features
#define NU 512       // units
#define N4U 2048     // 4*units
#define NSTEP 127    // 64 warmup + 63 rollout
#define WT_LD 520    // 512 + 8 fp16 pad (65 16B-granules/row -> conflict-free b128)

#define SM_WT_BYTES (128 * WT_LD * 2)          // 133120 B: W^T slice, fp16
#define SM_XS_OFF   SM_WT_BYTES                // x stage: float[128*3]
#define SM_TOTAL    (SM_XS_OFF + 128 * 3 * 4)  // 134656 B

// ws layout
#define WS_PP_OFF   (16 * 1024)                // pred partials after flag area
#define WS_H_OFF    (1u << 20)                 // h double buffer: 2 x 2 MB fp16
#define PP_PAR_STRIDE (16 * 16 * 128 * 3)      // floats per parity buffer
#define PP_BT_STRIDE  (16 * 128 * 3)
#define PP_UG_STRIDE  (128 * 3)

__device__ __forceinline__ float fast_rcp(float x) { return __builtin_amdgcn_rcpf(x); }
__device__ __forceinline__ float sigf(float x) { return fast_rcp(1.f + __expf(-x)); }
__device__ __forceinline__ float tanhf_fast(float x) {
    float a = fabsf(x);
    float e = __expf(-2.f * a);
    float t = (1.f - e) * fast_rcp(1.f + e);
    return copysignf(t, x);
}

__global__ __launch_bounds__(256, 1)
void lstm_feedback_kernel(const float* __restrict__ inputs, const float* __restrict__ kernw,
                          const float* __restrict__ rec, const float* __restrict__ bias,
                          const float* __restrict__ dw, const float* __restrict__ db,
                          float* __restrict__ out, float* __restrict__ pp,
                          f16* __restrict__ hbuf, unsigned* __restrict__ flags)
{
    extern __shared__ char smem[];
    f16* Wt = (f16*)smem;                         // [128 cols][WT_LD k] fp16
    float* x_s = (float*)(smem + SM_XS_OFF);      // [128][3]

    const int tid = threadIdx.x;
    const int bid = blockIdx.x;
    // Swizzle so the 16 blocks of one bt share bid%8 (same XCD under round-robin).
    const int xcd = bid & 7;
    const int jj  = bid >> 3;
    const int bt  = (xcd << 1) | (jj & 1);   // b-tile 0..15 (the sync domain)
    const int ug  = jj >> 1;                 // u-group 0..15
    const int uBase = ug * 32;
    const int bBase = bt * 128;
    const int w  = tid >> 6;          // wave 0..3 (splits b)
    const int l  = tid & 63;
    const int l31 = l & 31;
    const int hf  = l >> 5;           // half-wave
    unsigned* myflags = flags + bt * 32;  // 16 dwords used, 128B stride per bt

    // ---- stage W^T slice into LDS as fp16 (cols = 4 gates x 32 u), once
    {
        const int c  = tid & 127;
        const int kk = tid >> 7;
        const int gcol = ((c >> 5) * 512) + uBase + (c & 31);
        for (int k = kk; k < NU; k += 2)
            Wt[c * WT_LD + k] = (f16)rec[k * N4U + gcol];
    }

    // ---- per-lane constants
    float kr[4][3], br[4], dwr[3], dbr[3];
    #pragma unroll
    for (int ct = 0; ct < 4; ++ct) {
        const int gcol = ct * 512 + uBase + l31;
        #pragma unroll
        for (int f = 0; f < 3; ++f) kr[ct][f] = kernw[f * N4U + gcol];
        br[ct] = bias[gcol];
    }
    {
        const int u = uBase + l31;
        #pragma unroll
        for (int j = 0; j < 3; ++j) { dwr[j] = dw[u * 3 + j]; dbr[j] = db[j]; }
    }
    __syncthreads();

    float c_reg[16];
    #pragma unroll
    for (int r = 0; r < 16; ++r) c_reg[r] = 0.f;

    const size_t HB = (size_t)NB * NU;
    const int bW = bBase + w * 32;
    const size_t aoff = (size_t)(bW + l31) * NU + hf * 8;
    const f16* bptr = Wt + (size_t)l31 * WT_LD + hf * 8;

    for (int s = 0; s < NSTEP; ++s) {
        // ---- acquire: wait for the 16 peer flags, then one L1/L2 invalidate per CU
        if (s > 0) {
            if (tid < 16) {
                const unsigned* fp = myflags + tid;
                unsigned v;
                do {
                    v = __hip_atomic_load(fp, __ATOMIC_RELAXED, __HIP_MEMORY_SCOPE_AGENT);
                } while (v < (unsigned)s);
            }
            __syncthreads();
            if (w == 0) asm volatile("buffer_inv sc1" ::: "memory");
            __syncthreads();
        }

        // ---- stage x (warmup: inputs[:,s,:]; rollout: sum of pred partials)
        if (tid < 128) {
            float v0, v1, v2;
            if (s < SEQ) {
                const float* xp = inputs + ((size_t)(bBase + tid) * SEQ + s) * NF;
                v0 = xp[0]; v1 = xp[1]; v2 = xp[2];
            } else {
                const float* p = pp + (size_t)((s + 1) & 1) * PP_PAR_STRIDE
                               + bt * PP_BT_STRIDE + tid * 3;
                v0 = dbr[0]; v1 = dbr[1]; v2 = dbr[2];
                #pragma unroll
                for (int g = 0; g < 16; ++g) {
                    v0 += p[g * PP_UG_STRIDE + 0];
                    v1 += p[g * PP_UG_STRIDE + 1];
                    v2 += p[g * PP_UG_STRIDE + 2];
                }
                if (ug == 0) {  // final output: each pred element stored exactly once
                    float* o = out + ((size_t)(s - SEQ) * NB + bBase + tid) * 3;
                    o[0] = v0; o[1] = v1; o[2] = v2;
                }
            }
            x_s[tid * 3 + 0] = v0;
            x_s[tid * 3 + 1] = v1;
            x_s[tid * 3 + 2] = v2;
        }
        __syncthreads();

        f32x16 acc0 = {}, acc1 = {}, acc2 = {}, acc3 = {};
        if (s > 0) {
            const f16* ap = hbuf + (size_t)(s & 1) * HB + aoff;
            #pragma unroll 8
            for (int kt = 0; kt < 32; ++kt) {
                const int k0 = kt * 16;
                f16x8 a  = *(const f16x8*)(ap + k0);
                f16x8 b0 = *(const f16x8*)(bptr + 0 * 32 * WT_LD + k0);
                f16x8 b1 = *(const f16x8*)(bptr + 1 * 32 * WT_LD + k0);
                f16x8 b2 = *(const f16x8*)(bptr + 2 * 32 * WT_LD + k0);
                f16x8 b3 = *(const f16x8*)(bptr + 3 * 32 * WT_LD + k0);
                acc0 = __builtin_amdgcn_mfma_f32_32x32x16_f16(a, b0, acc0, 0, 0, 0);
                acc1 = __builtin_amdgcn_mfma_f32_32x32x16_f16(a, b1, acc1, 0, 0, 0);
                acc2 = __builtin_amdgcn_mfma_f32_32x32x16_f16(a, b2, acc2, 0, 0, 0);
                acc3 = __builtin_amdgcn_mfma_f32_32x32x16_f16(a, b3, acc3, 0, 0, 0);
            }
        }

        // ---- gates + state update + h write (sc1 = IF write-through, no wbl2 needed)
        f16* hw = hbuf + (size_t)((s & 1) ^ 1) * HB;
        const int n_out = s - (SEQ - 1);
        float* ppw = pp + (size_t)(s & 1) * PP_PAR_STRIDE + bt * PP_BT_STRIDE + ug * PP_UG_STRIDE;
        #pragma unroll
        for (int r = 0; r < 16; ++r) {
            const int mrow = (r & 3) + ((r >> 2) << 3) + (hf << 2);
            const int mloc = (w << 5) + mrow;
            const float x0 = x_s[mloc * 3 + 0];
            const float x1 = x_s[mloc * 3 + 1];
            const float x2 = x_s[mloc * 3 + 2];
            float z0 = acc0[r] + x0 * kr[0][0] + x1 * kr[0][1] + x2 * kr[0][2] + br[0];
            float z1 = acc1[r] + x0 * kr[1][0] + x1 * kr[1][1] + x2 * kr[1][2] + br[1];
            float z2 = acc2[r] + x0 * kr[2][0] + x1 * kr[2][1] + x2 * kr[2][2] + br[2];
            float z3 = acc3[r] + x0 * kr[3][0] + x1 * kr[3][1] + x2 * kr[3][2] + br[3];
            const float gi = sigf(z0);
            const float gf = sigf(z1);
            const float gg = tanhf_fast(z2);
            const float go = sigf(z3);
            const float cv = gf * c_reg[r] + gi * gg;
            c_reg[r] = cv;
            const float h2 = go * tanhf_fast(cv);
            {
                f16* ha = hw + (size_t)(bBase + mloc) * NU + uBase + l31;
                unsigned hb = (unsigned)__builtin_bit_cast(unsigned short, (f16)h2);
                asm volatile("global_store_short %0, %1, off sc1"
                             :: "v"(ha), "v"(hb) : "memory");
            }

            if (n_out >= 0) {
                #pragma unroll
                for (int j = 0; j < 3; ++j) {
                    float v = h2 * dwr[j];
                    #pragma unroll
                    for (int m = 1; m < 32; m <<= 1) v += __shfl_xor(v, m, 64);
                    if (l31 == r)
                        __hip_atomic_store(&ppw[mloc * 3 + j], v,
                                           __ATOMIC_RELAXED, __HIP_MEMORY_SCOPE_AGENT);
                }
            }
        }

        // ---- release: drain own sc1 stores (ack = IF-visible), barrier, flag store
        asm volatile("s_waitcnt vmcnt(0)" ::: "memory");
        __syncthreads();
        if (tid == 0)
            __hip_atomic_store(myflags + ug, (unsigned)(s + 1),
                               __ATOMIC_RELAXED, __HIP_MEMORY_SCOPE_AGENT);
    }

    // ---- epilogue: pred slot 63 (partials from step 126, parity 0)
    if (ug == 0) {
        if (tid < 16) {
            const unsigned* fp = myflags + tid;
            unsigned v;
            do {
                v = __hip_atomic_load(fp, __ATOMIC_RELAXED, __HIP_MEMORY_SCOPE_AGENT);
            } while (v < (unsigned)NSTEP);
        }
        __syncthreads();
        if (w == 0) asm volatile("buffer_inv sc1" ::: "memory");
        __syncthreads();
        if (tid < 128) {
            const float* p = pp + bt * PP_BT_STRIDE + tid * 3;   // parity 0
            float v0 = dbr[0], v1 = dbr[1], v2 = dbr[2];
            #pragma unroll
            for (int g = 0; g < 16; ++g) {
                v0 += p[g * PP_UG_STRIDE + 0];
                v1 += p[g * PP_UG_STRIDE + 1];
                v2 += p[g * PP_UG_STRIDE + 2];
            }
            float* o = out + ((size_t)63 * NB + bBase + tid) * 3;
            o[0] = v0; o[1] = v1; o[2] = v2;
        }
    }
}

extern "C" void kernel_launch(void* const* d_in, const int* in_sizes, int n_in,
                              void* d_out, int out_size, void* d_ws, size_t ws_size,
                              hipStream_t stream) {
    const float* inputs = (const float*)d_in[0];
    const float* kernw  = (const float*)d_in[1];
    const float* rec    = (const float*)d_in[2];
    const float* bias   = (const float*)d_in[3];
    const float* dw     = (const float*)d_in[4];
    const float* db     = (const float*)d_in[5];
    float* out = (float*)d_out;

    unsigned* flags = (unsigned*)d_ws;                     // 16 x 128B flag lines
    float* pp  = (float*)((char*)d_ws + WS_PP_OFF);        // pred partials, 2 parities
    f16* hbuf  = (f16*)((char*)d_ws + WS_H_OFF);           // double-buffered h: 2 x 2 MB

    hipMemsetAsync(d_ws, 0, 16 * 1024, stream);            // zero flags

    hipFuncSetAttribute(reinterpret_cast<const void*>(lstm_feedback_kernel),
                        hipFuncAttributeMaxDynamicSharedMemorySize, SM_TOTAL);

    void* args[] = { (void*)&inputs, (void*)&kernw, (void*)&rec, (void*)&bias,
                     (void*)&dw, (void*)&db, (void*)&out, (void*)&pp,
                     (void*)&hbuf, (void*)&flags };
    hipLaunchCooperativeKernel(reinterpret_cast<const void*>(lstm_feedback_kernel),
                               dim3(256), dim3(256), args, SM_TOTAL, stream);
}